// Round 3
// baseline (120.022 us; speedup 1.0000x reference)
//
#include <hip/hip_runtime.h>

typedef unsigned short u16;
typedef unsigned int u32;
typedef __attribute__((ext_vector_type(8))) short bf16x8;
typedef __attribute__((ext_vector_type(4))) float f32x4;

#define NUM_OPS 8
#define M_DIM 4096   // B*T = 8*512
#define K_DIM 1024
#define N_DIM 1024
#define BK 32
#define PITCH 40     // u16 per LDS row (80B): 16B-aligned rows, bank-stride 20 (breaks 16-bank pattern)
#define KITERS (K_DIM / BK)

// ---- helpers ----------------------------------------------------------

__device__ __forceinline__ int compute_idx(const float* __restrict__ logits,
                                           const float* __restrict__ u) {
  // argmax(log_softmax(logits) + gumbel) == argmax(logits - log(-log(u)))
  int best = 0; float bv = -3.4e38f;
#pragma unroll
  for (int i = 0; i < NUM_OPS; ++i) {
    float g = -logf(-logf(u[i]));
    float v = logits[i] + g;
    if (v > bv) { bv = v; best = i; }
  }
  return best;
}

// pack two f32 -> (bf16(b)<<16)|bf16(a), round-half-up (≈RNE, 5 VALU ops)
__device__ __forceinline__ u32 pk2(float a, float b) {
  u32 ua = __float_as_uint(a) + 0x8000u;
  u32 ub = __float_as_uint(b) + 0x8000u;
  return (ua >> 16) | (ub & 0xffff0000u);
}

// ---- fused: idx select + convert + GEMM + bias ------------------------
// C[m][n] = sum_k x[m][k] * W[idx][k][n] + b[idx][n]
// BM=128, BN=128, BK=32; 512 thr = 8 waves (2 m-rows x 4 n-cols), wave tile 64x32.
// A staged from x fp32 (contiguous float4), B from W fp32 (k-strided dword
// gather, lane-coalesced along n); both converted to bf16 into padded LDS.
// Reg-buffered prefetch: loads for k+1 issued before compute on k.
__global__ __launch_bounds__(512) void fused_kernel(
    const float* __restrict__ x, const float* __restrict__ W,
    const float* __restrict__ bvec, const float* __restrict__ logits,
    const float* __restrict__ u, float* __restrict__ out) {
  __shared__ u16 sA[2][128 * PITCH];  // [buf][m][k] 10KB each
  __shared__ u16 sB[2][128 * PITCH];  // [buf][n][k] 10KB each

  const int tid = threadIdx.x;
  const int w = tid >> 6, L = tid & 63;
  const int m0 = blockIdx.y * 128;
  const int n0 = blockIdx.x * 128;

  const int idx = compute_idx(logits, u);
  const float* Wi = W + (size_t)idx * K_DIM * N_DIM;

  // A staging: row am = tid>>2 (128 rows), kq = tid&3 -> 8 contiguous floats
  const int am = tid >> 2, akq = tid & 3;
  const float* gA = x + (size_t)(m0 + am) * K_DIM + akq * 8;
  const int lA = am * PITCH + akq * 8;  // u16 units, 16B-aligned

  // B staging: n = tid&127, kg = tid>>7 -> 8 k-strided dwords at fixed n
  const int bn = tid & 127, bkg = tid >> 7;
  const float* gB = Wi + (size_t)(bkg * 8) * N_DIM + n0 + bn;
  const int lB = bn * PITCH + bkg * 8;

  const int wm = w & 1, wn = w >> 1;
  int aoff[4], boff[2];
#pragma unroll
  for (int mt = 0; mt < 4; ++mt)
    aoff[mt] = (64 * wm + 16 * mt + (L & 15)) * PITCH + (L >> 4) * 8;
#pragma unroll
  for (int nt = 0; nt < 2; ++nt)
    boff[nt] = (32 * wn + 16 * nt + (L & 15)) * PITCH + (L >> 4) * 8;

  f32x4 acc[4][2] = {};

  // preload k-block 0 into registers
  float4 ra0 = *(const float4*)(gA);
  float4 ra1 = *(const float4*)(gA + 4);
  float rb[8];
#pragma unroll
  for (int j = 0; j < 8; ++j) rb[j] = gB[(size_t)j * N_DIM];

  for (int kk = 0; kk < KITERS; ++kk) {
    const int cur = kk & 1;
    // convert current regs -> LDS buf[cur]
    uint4 pa; pa.x = pk2(ra0.x, ra0.y); pa.y = pk2(ra0.z, ra0.w);
    pa.z = pk2(ra1.x, ra1.y); pa.w = pk2(ra1.z, ra1.w);
    *(uint4*)(&sA[cur][lA]) = pa;
    uint4 pb; pb.x = pk2(rb[0], rb[1]); pb.y = pk2(rb[2], rb[3]);
    pb.z = pk2(rb[4], rb[5]); pb.w = pk2(rb[6], rb[7]);
    *(uint4*)(&sB[cur][lB]) = pb;
    __syncthreads();  // one barrier per iter: write(cur) -> read(cur)

    if (kk + 1 < KITERS) {
      // issue k+1 global loads now; frag reads + MFMA below cover the latency
      const float* gA2 = gA + (kk + 1) * BK;
      ra0 = *(const float4*)(gA2);
      ra1 = *(const float4*)(gA2 + 4);
      const float* gB2 = gB + (size_t)(kk + 1) * BK * N_DIM;
#pragma unroll
      for (int j = 0; j < 8; ++j) rb[j] = gB2[(size_t)j * N_DIM];
    }

    bf16x8 af[4], bf[2];
#pragma unroll
    for (int mt = 0; mt < 4; ++mt) af[mt] = *(const bf16x8*)(&sA[cur][aoff[mt]]);
#pragma unroll
    for (int nt = 0; nt < 2; ++nt) bf[nt] = *(const bf16x8*)(&sB[cur][boff[nt]]);
#pragma unroll
    for (int mt = 0; mt < 4; ++mt)
#pragma unroll
      for (int nt = 0; nt < 2; ++nt)
        acc[mt][nt] = __builtin_amdgcn_mfma_f32_16x16x32_bf16(
            af[mt], bf[nt], acc[mt][nt], 0, 0, 0);
    // no trailing barrier: next iter writes buf[1-cur], whose readers all
    // passed this iter's barrier already
  }

  // epilogue: C/D layout col=lane&15, row=(lane>>4)*4+reg
  const float* bi = bvec + (size_t)idx * N_DIM;
#pragma unroll
  for (int mt = 0; mt < 4; ++mt) {
    int row = m0 + 64 * wm + 16 * mt + (L >> 4) * 4;
#pragma unroll
    for (int nt = 0; nt < 2; ++nt) {
      int col = n0 + 32 * wn + 16 * nt + (L & 15);
      float bv = bi[col];
#pragma unroll
      for (int r = 0; r < 4; ++r)
        out[(size_t)(row + r) * N_DIM + col] = acc[mt][nt][r] + bv;
    }
  }
}

// ---- launch -----------------------------------------------------------

extern "C" void kernel_launch(void* const* d_in, const int* in_sizes, int n_in,
                              void* d_out, int out_size, void* d_ws, size_t ws_size,
                              hipStream_t stream) {
  const float* x      = (const float*)d_in[0];
  const float* W      = (const float*)d_in[1];
  const float* bvec   = (const float*)d_in[2];
  const float* logits = (const float*)d_in[3];
  const float* u      = (const float*)d_in[4];
  float* out = (float*)d_out;

  dim3 grid(N_DIM / 128, M_DIM / 128);  // 8 x 32 = 256 blocks = 1/CU
  fused_kernel<<<grid, 512, 0, stream>>>(x, W, bvec, logits, u, out);
}